// Round 2
// baseline (95.383 us; speedup 1.0000x reference)
//
#include <hip/hip_runtime.h>
#include <math.h>

// Problem constants (from reference)
#define BB 4096
#define PP 128
#define GG 128

// SCALE = SPACE_SIZE / (VOXELS_PER_AXIS - 1), BIAS = SPACE_CENTER - SPACE_SIZE/2
#define SCALE_X (8000.0f / 79.0f)
#define SCALE_Y (8000.0f / 79.0f)
#define SCALE_Z (2000.0f / 19.0f)
#define BIAS_X (-4000.0f)
#define BIAS_Y (-4000.0f)
#define BIAS_Z (0.0f)

#define DIST_THRESH_SQ (500.0f * 500.0f)
#define BBOX_THRESH 0.1f
#define SENTINEL 1.0e18f

__global__ __launch_bounds__(PP) void proposal_layer_kernel(
    const int* __restrict__ topk_index,        // [B, P, 3]
    const float* __restrict__ topk_confs,      // [B, P]
    const float* __restrict__ match_bbox_preds,// [B, P, 2]
    const float* __restrict__ roots_3d,        // [B, G, 3]
    const float* __restrict__ gt_bbox,         // [B, G, 2]
    const int* __restrict__ num_person,        // [B]
    float* __restrict__ out)                   // [B, P, 7]
{
    const int b = blockIdx.x;
    const int p = threadIdx.x;

    __shared__ float4 s_roots[GG];   // padded rows: one ds_read_b128 per g
    __shared__ float2 s_bbox[GG];
    __shared__ float  s_out[PP * 7];

    const int np = num_person[b];

    // Stage roots (conditional: rows >= np get sentinel instead, no race).
    float* s_rootsf = (float*)s_roots;
    const float* rb = roots_3d + (size_t)b * GG * 3;
    #pragma unroll
    for (int k = 0; k < 3; ++k) {
        const int i = p + k * PP;      // i in [0, 384)
        const int g = i / 3;
        const int c = i - g * 3;
        if (g < np) s_rootsf[g * 4 + c] = rb[i];
    }
    if (p >= np) {
        s_roots[p] = make_float4(SENTINEL, SENTINEL, SENTINEL, 0.0f);
    }
    // Stage gt bboxes (rows >= np are never read: besti always < np).
    {
        const float2* gbb = (const float2*)(gt_bbox + (size_t)b * GG * 2);
        s_bbox[p] = gbb[p];
    }
    __syncthreads();

    // voxel index -> world coords
    const size_t bp = (size_t)b * PP + p;
    const int ix = topk_index[bp * 3 + 0];
    const int iy = topk_index[bp * 3 + 1];
    const int iz = topk_index[bp * 3 + 2];
    const float cx = (float)ix * SCALE_X + BIAS_X;
    const float cy = (float)iy * SCALE_Y + BIAS_Y;
    const float cz = (float)iz * SCALE_Z + BIAS_Z;

    // Nearest valid GT. Trip count rounded to 16 (sentinel rows never win),
    // fixed unroll so LDS reads pipeline ahead of the compare chain.
    const int npr = (np + 15) & ~15;
    float best = INFINITY;
    int besti = 0;
    #pragma unroll 16
    for (int g = 0; g < npr; ++g) {
        const float4 r = s_roots[g];
        const float dx = cx - r.x;
        const float dy = cy - r.y;
        const float dz = cz - r.z;
        const float d2 = dx * dx + dy * dy + dz * dz;
        if (d2 < best) { best = d2; besti = g; }   // strict < == first-min (jnp.argmin)
    }

    const float p2g = (best > DIST_THRESH_SQ) ? -1.0f : (float)besti;
    const int safe = (p2g < 0.0f) ? 0 : besti;     // clip(-1,0,G-1) -> 0
    const float mb0 = s_bbox[safe].x;
    const float mb1 = s_bbox[safe].y;

    const float2 pb = ((const float2*)match_bbox_preds)[bp];
    const bool overwrite = (p2g >= 0.0f) &&
                           ((pb.x < mb0 - BBOX_THRESH) || (pb.y < mb1 - BBOX_THRESH));
    const float o0 = overwrite ? mb0 : pb.x;
    const float o1 = overwrite ? mb1 : pb.y;

    // Stage [128][7] outputs in LDS, then coalesced float4 writes.
    s_out[p * 7 + 0] = cx;
    s_out[p * 7 + 1] = cy;
    s_out[p * 7 + 2] = cz;
    s_out[p * 7 + 3] = p2g;
    s_out[p * 7 + 4] = topk_confs[bp];
    s_out[p * 7 + 5] = o0;
    s_out[p * 7 + 6] = o1;
    __syncthreads();

    // Block's out region: 896 floats = 224 float4, base offset b*3584 B (16B-aligned).
    float4* outv = (float4*)(out + (size_t)b * PP * 7);
    const float4* s_outv = (const float4*)s_out;
    #pragma unroll
    for (int k = 0; k < 2; ++k) {
        const int i = p + k * PP;
        if (i < 224) outv[i] = s_outv[i];
    }
}

extern "C" void kernel_launch(void* const* d_in, const int* in_sizes, int n_in,
                              void* d_out, int out_size, void* d_ws, size_t ws_size,
                              hipStream_t stream) {
    const int* topk_index = (const int*)d_in[0];
    const float* topk_confs = (const float*)d_in[1];
    const float* match_bbox_preds = (const float*)d_in[2];
    const float* roots_3d = (const float*)d_in[3];
    const float* gt_bbox = (const float*)d_in[4];
    const int* num_person = (const int*)d_in[5];
    float* out = (float*)d_out;

    proposal_layer_kernel<<<BB, PP, 0, stream>>>(
        topk_index, topk_confs, match_bbox_preds, roots_3d, gt_bbox, num_person, out);
}